// Round 10
// baseline (318.194 us; speedup 1.0000x reference)
//
#include <hip/hip_runtime.h>
#include <math.h>

// Problem constants (B=4, S=4096, H=4096, E=64, top_k=8)
#define TOKENS 16384   // B*S
#define HDIM   4096
#define NEXP   64
#define TOPK   8

#define TAU 1.5e-4f    // margin: |logit err| bound ~ TAU/3; RMS err ~3e-6 -> 50 sigma

typedef short bf16x8 __attribute__((ext_vector_type(8)));
typedef float f32x4  __attribute__((ext_vector_type(4)));

__device__ __forceinline__ unsigned bf16_rne(float f) {          // RNE fp32->bf16 bits
    unsigned u = __float_as_uint(f);
    return (u + 0x7fffu + ((u >> 16) & 1u)) >> 16;
}
__device__ __forceinline__ float bf16_tof(unsigned h) { return __uint_as_float(h << 16); }

// ================= B pre-split: wgt fp32 -> 3 bf16 planes in d_ws ==============
__global__ __launch_bounds__(256) void bsplit_kernel(const float* __restrict__ wgt,
                                                     short* __restrict__ bsp,
                                                     int* __restrict__ cnt) {
    if (blockIdx.x == 0 && threadIdx.x == 0) *cnt = 0;   // reset recheck worklist
    const int base = 4 * (blockIdx.x * 256 + threadIdx.x);        // 64*4096 elems / 4
    float4 w = *reinterpret_cast<const float4*>(wgt + base);
    float f[4] = {w.x, w.y, w.z, w.w};
    short h0[4], h1[4], h2[4];
#pragma unroll
    for (int e = 0; e < 4; ++e) {
        unsigned b0 = bf16_rne(f[e]); float r1 = f[e] - bf16_tof(b0);
        unsigned b1 = bf16_rne(r1);   float r2 = r1 - bf16_tof(b1);
        unsigned b2 = bf16_rne(r2);
        h0[e] = (short)b0; h1[e] = (short)b1; h2[e] = (short)b2;
    }
    *reinterpret_cast<short4*>(bsp + 0 * 262144 + base) = make_short4(h0[0], h0[1], h0[2], h0[3]);
    *reinterpret_cast<short4*>(bsp + 1 * 262144 + base) = make_short4(h1[0], h1[1], h1[2], h1[3]);
    *reinterpret_cast<short4*>(bsp + 2 * 262144 + base) = make_short4(h2[0], h2[1], h2[2], h2[3]);
}

// ================= GEMM: bf16x3 split-product MFMA ============================
// logits[t][e] = dot(hid[t], wgt[e]).  a = a0+a1+a2 (bf16 triplet, ~26 bits);
// acc += a0b0 + a0b1 + a1b0 + a0b2 + a1b1 + a2b0 (neglected terms ~2^-27 rel).
// fp32 accumulation; error certified downstream by the margin test + recheck.
// A staged+split in LDS (shared by 4 waves); B-frags straight from L2 (bsp,
// 1.5 MB). Nothing is in flight at a barrier that hasn't already landed.
#define BMg 32
#define BKg 32
#define GCH (HDIM / BKg)   // 128
#define LDH 40             // bf16 row stride (80 B: 16B-aligned frags, spread banks)

__global__ __launch_bounds__(256) void gemm_bf16x3(const float* __restrict__ hid,
                                                   const short* __restrict__ bsp,
                                                   float* __restrict__ logits) {
    __shared__ short Abf[2][3][BMg][LDH];   // 15.4 KB

    const int tid  = threadIdx.x;
    const int bm   = blockIdx.x * BMg;
    const int wv   = tid >> 6, lane = tid & 63;
    const int r    = lane & 15;        // operand free index
    const int q    = lane >> 4;        // k-block (8 consecutive k per slot group)
    const int th   = wv & 1;           // token half (16 rows)
    const int ch   = wv >> 1;          // expert half (32 cols, 2 col-tiles)

    // ---- C/D layout self-calibration (probe MFMAs; any bijective layout) ----
    const short hr  = (short)bf16_rne((float)r);
    const short one = (short)0x3F80;
    bf16x8 pav = {hr, hr, hr, hr, hr, hr, hr, hr};
    bf16x8 pbv = {one, one, one, one, one, one, one, one};
    f32x4 z = {0.f, 0.f, 0.f, 0.f};
    f32x4 rowp = __builtin_amdgcn_mfma_f32_16x16x32_bf16(pav, pbv, z, 0, 0, 0);
    f32x4 colp = __builtin_amdgcn_mfma_f32_16x16x32_bf16(pbv, pav, z, 0, 0, 0);
    int drow[4], dcol[4];
#pragma unroll
    for (int j = 0; j < 4; ++j) {
        drow[j] = (int)(rowp[j] * (1.f / 32.f) + 0.5f);
        dcol[j] = (int)(colp[j] * (1.f / 32.f) + 0.5f);
    }

    f32x4 acc0 = z, acc1 = z;          // col-tile 0 / 1

    // staging: A chunk = 32 rows x 32 k fp32 = 256 float4; thread -> (row, f)
    const int srow = tid >> 3, sf = tid & 7;
    const float* Asrc = hid + (size_t)(bm + srow) * HDIM + 4 * sf;

    float4 paA, paB;                   // A prefetch register sets (distance 2)
    bf16x8 bA[2][3], bB[2][3];         // B fragment sets [ct][split] (distance 1)

#define LOADA(DST, C) do { \
        const int kc_ = ((C) < GCH ? (C) : GCH - 1) * BKg; \
        DST = *reinterpret_cast<const float4*>(Asrc + kc_); \
    } while (0)

#define LOADB(DST, C) do { \
        const int kc_ = ((C) < GCH ? (C) : GCH - 1) * BKg + 8 * q; \
        _Pragma("unroll") \
        for (int ct_ = 0; ct_ < 2; ++ct_) \
        { _Pragma("unroll") \
          for (int s_ = 0; s_ < 3; ++s_) \
            DST[ct_][s_] = *reinterpret_cast<const bf16x8*>( \
                bsp + ((size_t)s_ * NEXP + 32 * ch + 16 * ct_ + r) * HDIM + kc_); } \
    } while (0)

#define SPLITW(SRC, BUF) do { \
        float f_[4] = {SRC.x, SRC.y, SRC.z, SRC.w}; \
        short g0_[4], g1_[4], g2_[4]; \
        _Pragma("unroll") \
        for (int e_ = 0; e_ < 4; ++e_) { \
            unsigned b0_ = bf16_rne(f_[e_]); float r1_ = f_[e_] - bf16_tof(b0_); \
            unsigned b1_ = bf16_rne(r1_);    float r2_ = r1_ - bf16_tof(b1_); \
            unsigned b2_ = bf16_rne(r2_); \
            g0_[e_] = (short)b0_; g1_[e_] = (short)b1_; g2_[e_] = (short)b2_; } \
        *reinterpret_cast<short4*>(&Abf[BUF][0][srow][4 * sf]) = make_short4(g0_[0], g0_[1], g0_[2], g0_[3]); \
        *reinterpret_cast<short4*>(&Abf[BUF][1][srow][4 * sf]) = make_short4(g1_[0], g1_[1], g1_[2], g1_[3]); \
        *reinterpret_cast<short4*>(&Abf[BUF][2][srow][4 * sf]) = make_short4(g2_[0], g2_[1], g2_[2], g2_[3]); \
    } while (0)

#define COMPUTE(BUF, B) do { \
        bf16x8 a0_ = *reinterpret_cast<const bf16x8*>(&Abf[BUF][0][16 * th + r][8 * q]); \
        bf16x8 a1_ = *reinterpret_cast<const bf16x8*>(&Abf[BUF][1][16 * th + r][8 * q]); \
        bf16x8 a2_ = *reinterpret_cast<const bf16x8*>(&Abf[BUF][2][16 * th + r][8 * q]); \
        acc0 = __builtin_amdgcn_mfma_f32_16x16x32_bf16(a0_, B[0][0], acc0, 0, 0, 0); \
        acc1 = __builtin_amdgcn_mfma_f32_16x16x32_bf16(a0_, B[1][0], acc1, 0, 0, 0); \
        acc0 = __builtin_amdgcn_mfma_f32_16x16x32_bf16(a0_, B[0][1], acc0, 0, 0, 0); \
        acc1 = __builtin_amdgcn_mfma_f32_16x16x32_bf16(a0_, B[1][1], acc1, 0, 0, 0); \
        acc0 = __builtin_amdgcn_mfma_f32_16x16x32_bf16(a1_, B[0][0], acc0, 0, 0, 0); \
        acc1 = __builtin_amdgcn_mfma_f32_16x16x32_bf16(a1_, B[1][0], acc1, 0, 0, 0); \
        acc0 = __builtin_amdgcn_mfma_f32_16x16x32_bf16(a0_, B[0][2], acc0, 0, 0, 0); \
        acc1 = __builtin_amdgcn_mfma_f32_16x16x32_bf16(a0_, B[1][2], acc1, 0, 0, 0); \
        acc0 = __builtin_amdgcn_mfma_f32_16x16x32_bf16(a1_, B[0][1], acc0, 0, 0, 0); \
        acc1 = __builtin_amdgcn_mfma_f32_16x16x32_bf16(a1_, B[1][1], acc1, 0, 0, 0); \
        acc0 = __builtin_amdgcn_mfma_f32_16x16x32_bf16(a2_, B[0][0], acc0, 0, 0, 0); \
        acc1 = __builtin_amdgcn_mfma_f32_16x16x32_bf16(a2_, B[1][0], acc1, 0, 0, 0); \
    } while (0)

    // ---- prologue: invariant at even-c entry: paB=A(c+1), paA=A(c+2), bA=B(c)
    LOADA(paB, 0);
    LOADB(bA, 0);
    SPLITW(paB, 0);          // A(0) -> LDS[0]  (waitcnt auto before use)
    LOADA(paB, 1);
    LOADA(paA, 2);

    for (int c = 0; c < GCH; c += 2) {
        // ---- even: chunk c from LDS[0] ----
        __syncthreads();                       // LDS[0] ready; in-flight loads already landed
        LOADB(bB, c + 1);
        COMPUTE(0, bA);
        SPLITW(paB, 1);                        // A(c+1) -> LDS[1] (loaded 2 chunks ago)
        LOADA(paB, c + 3);
        // ---- odd: chunk c+1 from LDS[1] ----
        __syncthreads();
        LOADB(bA, c + 2);
        COMPUTE(1, bB);
        if (c + 2 < GCH) SPLITW(paA, 0);       // A(c+2) -> LDS[0]
        LOADA(paA, c + 4);
    }

#undef LOADA
#undef LOADB
#undef SPLITW
#undef COMPUTE

    // ---- epilogue: probe-derived scatter ----
#pragma unroll
    for (int j = 0; j < 4; ++j) {
        const int row = bm + 16 * th + drow[j];
        logits[(size_t)row * NEXP + 32 * ch + dcol[j]]      = acc0[j];
        logits[(size_t)row * NEXP + 32 * ch + 16 + dcol[j]] = acc1[j];
    }
}

// ======== top-k + softmax + margin certification (one wave per token) =========
__global__ __launch_bounds__(256) void topk_margin(const float* __restrict__ logits,
                                                   float* __restrict__ out_idx,
                                                   float* __restrict__ out_w,
                                                   int* __restrict__ cnt,
                                                   int* __restrict__ list) {
    const int wave  = threadIdx.x >> 6;
    const int lane  = threadIdx.x & 63;
    const int token = blockIdx.x * 4 + wave;
    if (token >= TOKENS) return;

    float v = logits[(size_t)token * NEXP + lane];

    float myval = 0.f; int myidx = 0; float max0 = 0.f;

#pragma unroll
    for (int k = 0; k < TOPK + 1; ++k) {       // top-9: rank-9 needed for margin
        float bv = v; int bi = lane;
#pragma unroll
        for (int off = 32; off > 0; off >>= 1) {   // argmax, tie -> lower index
            float ov = __shfl_xor(bv, off);
            int   oi = __shfl_xor(bi, off);
            if (ov > bv || (ov == bv && oi < bi)) { bv = ov; bi = oi; }
        }
        if (k == 0) max0 = bv;
        if (lane == k) { myval = bv; myidx = bi; }
        if (lane == bi) v = -INFINITY;
    }

    // margin check: all adjacent gaps in the top-9 must exceed TAU
    const float nxt = __shfl(myval, lane + 1);
    const bool  bad = (lane < TOPK) && (myval - nxt < TAU);
    const bool  flagged = __any(bad);

    float e = (lane < TOPK) ? expf(myval - max0) : 0.f;
    float s = e;
#pragma unroll
    for (int off = 4; off > 0; off >>= 1) s += __shfl_xor(s, off);

    if (lane < TOPK) {
        size_t o = (size_t)token * TOPK + lane;
        out_idx[o] = (float)myidx;
        out_w[o]   = e / s;
    }
    if (flagged && lane == 0) {
        int slot = atomicAdd(cnt, 1);
        if (slot < TOKENS) list[slot] = token;
    }
}

// ======== exact fp64 recheck of flagged tokens (ordering ground truth) ========
__global__ __launch_bounds__(256) void recheck_kernel(const float* __restrict__ hid,
                                                      const float* __restrict__ wgt,
                                                      const int* __restrict__ cnt,
                                                      const int* __restrict__ list,
                                                      float* __restrict__ out_idx,
                                                      float* __restrict__ out_w) {
    __shared__ double dlog[NEXP];
    const int tid  = threadIdx.x;
    const int wv   = tid >> 6, lane = tid & 63;
    const int eg   = lane >> 4;        // 0..3
    const int kl   = lane & 15;        // 16 k-lanes per expert
    const int n    = *cnt;

    for (int it = blockIdx.x; it < n && it < TOKENS; it += gridDim.x) {
        const int token = list[it];
        const float* hrow = hid + (size_t)token * HDIM;
#pragma unroll 1
        for (int pass = 0; pass < 4; ++pass) {
            const int e = wv * 16 + pass * 4 + eg;
            const float* wrow = wgt + (size_t)e * HDIM;
            double p = 0.0;
            for (int k0 = kl * 4; k0 < HDIM; k0 += 64) {
                float4 hv = *reinterpret_cast<const float4*>(hrow + k0);
                float4 wl = *reinterpret_cast<const float4*>(wrow + k0);
                p = fma((double)hv.x, (double)wl.x, p);
                p = fma((double)hv.y, (double)wl.y, p);
                p = fma((double)hv.z, (double)wl.z, p);
                p = fma((double)hv.w, (double)wl.w, p);
            }
#pragma unroll
            for (int off = 8; off > 0; off >>= 1) p += __shfl_xor(p, off);
            if (kl == 0) dlog[e] = p;
        }
        __syncthreads();
        if (wv == 0) {
            double v = dlog[lane];
            double myval = 0.0; int myidx = 0; double m0 = 0.0;
#pragma unroll
            for (int k = 0; k < TOPK; ++k) {
                double bv = v; int bi = lane;
#pragma unroll
                for (int off = 32; off > 0; off >>= 1) {
                    double ov = __shfl_xor(bv, off);
                    int    oi = __shfl_xor(bi, off);
                    if (ov > bv || (ov == bv && oi < bi)) { bv = ov; bi = oi; }
                }
                if (k == 0) m0 = bv;
                if (lane == k) { myval = bv; myidx = bi; }
                if (lane == bi) v = -INFINITY;
            }
            double ee = (lane < TOPK) ? exp(myval - m0) : 0.0;
            double ss = ee;
#pragma unroll
            for (int off = 4; off > 0; off >>= 1) ss += __shfl_xor(ss, off);
            if (lane < TOPK) {
                size_t o = (size_t)token * TOPK + lane;
                out_idx[o] = (float)myidx;
                out_w[o]   = (float)(ee / ss);
            }
        }
        __syncthreads();
    }
}

extern "C" void kernel_launch(void* const* d_in, const int* in_sizes, int n_in,
                              void* d_out, int out_size, void* d_ws, size_t ws_size,
                              hipStream_t stream) {
    const float* hid = (const float*)d_in[0];
    const float* wgt = (const float*)d_in[1];

    float* logits  = (float*)d_out;
    float* out_idx = logits + (size_t)TOKENS * NEXP;
    float* out_w   = out_idx + (size_t)TOKENS * TOPK;

    short* bsp  = (short*)d_ws;                                  // 3*64*4096 bf16 = 1.5 MB
    int*   cnt  = (int*)((char*)d_ws + 3 * NEXP * HDIM * 2);     // worklist counter
    int*   list = cnt + 1;                                       // worklist (<= TOKENS ints)

    bsplit_kernel <<<256, 256, 0, stream>>>(wgt, bsp, cnt);
    gemm_bf16x3   <<<TOKENS / BMg, 256, 0, stream>>>(hid, bsp, logits);
    topk_margin   <<<TOKENS / 4, 256, 0, stream>>>(logits, out_idx, out_w, cnt, list);
    recheck_kernel<<<256, 256, 0, stream>>>(hid, wgt, cnt, list, out_idx, out_w);
}